// Round 13
// baseline (9795.403 us; speedup 1.0000x reference)
//
#include <hip/hip_runtime.h>
#include <hip/hip_bf16.h>
#include <cmath>

#define FPS_N 8192
#define FPS_K 4096
#define CS    256
#define FT    512          // FPS threads (8 waves)
#define PPT   16           // points per thread (register-resident)
#define NEGINF (-__builtin_inff())
#define KMAX  0x7fffffff
#define FPS_LDS (131072 + 128)   // float4[8192] mirror + int2[2][8] slots

// Minkowski-p3 "sum of |d|^3" with reference-exact f32 op order (no FMA contraction).
__device__ __forceinline__ float p3sum(float x, float y, float z,
                                       float nx, float ny, float nz) {
  float dx = fabsf(__fsub_rn(x, nx));
  float dy = fabsf(__fsub_rn(y, ny));
  float dz = fabsf(__fsub_rn(z, nz));
  float cx = __fmul_rn(__fmul_rn(dx, dx), dx);
  float cy = __fmul_rn(__fmul_rn(dy, dy), dy);
  float cz = __fmul_rn(__fmul_rn(dz, dz), dz);
  return __fadd_rn(__fadd_rn(cx, cy), cz);
}

// Squared Euclidean distance, reference-exact f32 op order.
__device__ __forceinline__ float eucl2(float x, float y, float z,
                                       float nx, float ny, float nz) {
  float dx = __fsub_rn(x, nx);
  float dy = __fsub_rn(y, ny);
  float dz = __fsub_rn(z, nz);
  return __fadd_rn(__fadd_rn(__fmul_rn(dx, dx), __fmul_rn(dy, dy)),
                   __fmul_rn(dz, dz));
}

#define LEXGT(va, ka, vb, kb) (((va) > (vb)) || ((va) == (vb) && ((ka) < (kb))))
#define SELP(va, ka, vb, kb) { bool t_ = LEXGT(vb, kb, va, ka); \
  va = t_ ? (vb) : (va); ka = t_ ? (kb) : (ka); }

template<int CTRL>
__device__ __forceinline__ int dppi(int a) {
  return __builtin_amdgcn_update_dpp(a, a, CTRL, 0xF, 0xF, false);
}
template<int CTRL>
__device__ __forceinline__ float dppf(float a) {
  return __int_as_float(__builtin_amdgcn_update_dpp(__float_as_int(a), __float_as_int(a), CTRL, 0xF, 0xF, false));
}

// DPP lex-max select: (v,k) with v float desc, k int asc tie-break.
template<int CTRL>
__device__ __forceinline__ void dpp_sel2(float& v, int& k) {
  float fv = dppf<CTRL>(v);
  int   nk = dppi<CTRL>(k);
  bool t = LEXGT(fv, nk, v, k);
  v = t ? fv : v;
  k = t ? nk : k;
}

// thread-local lex-max over 16 register (dd,key) pairs: 15 SELPs, 4 levels
#define RESCAN16() { \
  float v0 = dd[0], v1 = dd[1], v2 = dd[2], v3 = dd[3]; \
  float v4 = dd[4], v5 = dd[5], v6 = dd[6], v7 = dd[7]; \
  float v8 = dd[8], v9 = dd[9], vA = dd[10], vB = dd[11]; \
  float vC = dd[12], vD = dd[13], vE = dd[14], vF = dd[15]; \
  int j0 = key[0], j1 = key[1], j2 = key[2], j3 = key[3]; \
  int j4 = key[4], j5 = key[5], j6 = key[6], j7 = key[7]; \
  int j8 = key[8], j9 = key[9], jA = key[10], jB = key[11]; \
  int jC = key[12], jD = key[13], jE = key[14], jF = key[15]; \
  SELP(v0, j0, v1, j1) SELP(v2, j2, v3, j3) SELP(v4, j4, v5, j5) SELP(v6, j6, v7, j7) \
  SELP(v8, j8, v9, j9) SELP(vA, jA, vB, jB) SELP(vC, jC, vD, jD) SELP(vE, jE, vF, jF) \
  SELP(v0, j0, v2, j2) SELP(v4, j4, v6, j6) SELP(v8, j8, vA, jA) SELP(vC, jC, vE, jE) \
  SELP(v0, j0, v4, j4) SELP(v8, j8, vC, jC) SELP(v0, j0, v8, j8) \
  bv = v0; bkey = j0; }

// wave reduce (6-level DPP) -> lane 63 publishes (v,key) to slot sn
#define WAVE_PUB(sn) { \
  float rv = bv; int rk = bkey; \
  dpp_sel2<0x111>(rv, rk); dpp_sel2<0x112>(rv, rk); dpp_sel2<0x114>(rv, rk); \
  dpp_sel2<0x118>(rv, rk); dpp_sel2<0x142>(rv, rk); dpp_sel2<0x143>(rv, rk); \
  if (lane == 63) slots[(sn) * 8 + wave] = make_int2(__float_as_int(rv), rk); }

// ---------------------------------------------------------------------------
// 12-bit Morton (16x16x16 over [-4,4]^3) counting sort -> SoA px/py/pz + u16
// orig ids + zeroed selection flags (orig 0 pre-marked). (r7-proven)
// ---------------------------------------------------------------------------
__global__ __launch_bounds__(1024) void bin_kernel(const float* __restrict__ pos,
                                                   float* __restrict__ px,
                                                   float* __restrict__ py,
                                                   float* __restrict__ pz,
                                                   unsigned short* __restrict__ ids16,
                                                   unsigned char* __restrict__ selb) {
  __shared__ int hist[4096];
  __shared__ int part[1024];
  const int tid = threadIdx.x;
#pragma unroll
  for (int i = 0; i < 4; ++i) hist[tid * 4 + i] = 0;
  ((int*)selb)[tid * 2 + 0] = 0;
  ((int*)selb)[tid * 2 + 1] = 0;
  if (tid == 0) selb[0] = 1;
  __syncthreads();

  float qx[8], qy[8], qz[8];
  int cell[8];
  {
    const float4* p4 = (const float4*)pos + tid * 6;
    float4 a0 = p4[0], a1 = p4[1], a2 = p4[2], a3 = p4[3], a4 = p4[4], a5 = p4[5];
    qx[0]=a0.x; qy[0]=a0.y; qz[0]=a0.z;
    qx[1]=a0.w; qy[1]=a1.x; qz[1]=a1.y;
    qx[2]=a1.z; qy[2]=a1.w; qz[2]=a2.x;
    qx[3]=a2.y; qy[3]=a2.z; qz[3]=a2.w;
    qx[4]=a3.x; qy[4]=a3.y; qz[4]=a3.z;
    qx[5]=a3.w; qy[5]=a4.x; qz[5]=a4.y;
    qx[6]=a4.z; qy[6]=a4.w; qz[6]=a5.x;
    qx[7]=a5.y; qy[7]=a5.z; qz[7]=a5.w;
  }
#pragma unroll
  for (int j = 0; j < 8; ++j) {
    int ix = min(max((int)floorf((qx[j] + 4.0f) * 2.0f), 0), 15);
    int iy = min(max((int)floorf((qy[j] + 4.0f) * 2.0f), 0), 15);
    int iz = min(max((int)floorf((qz[j] + 4.0f) * 2.0f), 0), 15);
    int m = 0;
#pragma unroll
    for (int b = 0; b < 4; ++b)
      m |= (((ix >> b) & 1) << (3 * b)) | (((iy >> b) & 1) << (3 * b + 1)) |
           (((iz >> b) & 1) << (3 * b + 2));
    cell[j] = m;
    atomicAdd(&hist[m], 1);
  }
  __syncthreads();
  int h0 = hist[tid*4], h1 = hist[tid*4+1], h2 = hist[tid*4+2], h3 = hist[tid*4+3];
  int s = h0 + h1 + h2 + h3;
  part[tid] = s;
  __syncthreads();
  for (int off = 1; off < 1024; off <<= 1) {
    int u = (tid >= off) ? part[tid - off] : 0;
    __syncthreads();
    part[tid] += u;
    __syncthreads();
  }
  int base = part[tid] - s;
  hist[tid*4+0] = base;
  hist[tid*4+1] = base + h0;
  hist[tid*4+2] = base + h0 + h1;
  hist[tid*4+3] = base + h0 + h1 + h2;
  __syncthreads();
#pragma unroll
  for (int j = 0; j < 8; ++j) {
    int slot = atomicAdd(&hist[cell[j]], 1);
    px[slot] = qx[j];
    py[slot] = qy[j];
    pz[slot] = qz[j];
    ids16[slot] = (unsigned short)(tid * 8 + j);
  }
}

// ---------------------------------------------------------------------------
// FPS: 8 waves x 64 lanes x 16 register-resident Morton-sorted points.
// All per-point state (x,y,z,d2,dd,key) in VGPRs; LDS only holds a read-only
// coords mirror (winner lookup = one uniform broadcast read) + 8 slim (v,key)
// parity slots (3-level DPP merge). Conditional sqrt (d2 shadow): sqrt and
// candidate rescan only when the thread's candidate point actually changed
// (r1-proven invariant: slots always hold each wave's exact top-1).
// One barrier/iteration. Bit-exact: dd = sqrt(min d2) equals the reference
// recurrence (sqrt monotone + correctly rounded); lex tie-break on original
// index at every level; bbox gates conservative (0.999 margin).
// ---------------------------------------------------------------------------
__global__ __launch_bounds__(FT) void fps_kernel(const float* __restrict__ pos,
                                                 const float* __restrict__ spx,
                                                 const float* __restrict__ spy,
                                                 const float* __restrict__ spz,
                                                 const unsigned short* __restrict__ sid,
                                                 unsigned char* __restrict__ selb) {
  extern __shared__ char smem[];
  float4* lds4 = (float4*)smem;                 // 8192 coords (read-only after init)
  int2*   slots = (int2*)(smem + 131072);       // [parity][8 waves]
  const int tid = threadIdx.x, lane = tid & 63, wave = tid >> 6;

  // ---- coalesced LDS coords mirror ----
  for (int i = tid; i < FPS_N; i += FT)
    lds4[i] = make_float4(spx[i], spy[i], spz[i], 0.f);

  // ---- register state: 16 points/thread from global SoA ----
  float x[PPT], y[PPT], z[PPT], d2[PPT], dd[PPT];
  int key[PPT];
  const float p0x = pos[0], p0y = pos[1], p0z = pos[2];
  {
#pragma unroll
    for (int q = 0; q < 4; ++q) {
      float4 a = ((const float4*)spx)[tid * 4 + q];
      x[4*q+0] = a.x; x[4*q+1] = a.y; x[4*q+2] = a.z; x[4*q+3] = a.w;
      float4 b = ((const float4*)spy)[tid * 4 + q];
      y[4*q+0] = b.x; y[4*q+1] = b.y; y[4*q+2] = b.z; y[4*q+3] = b.w;
      float4 c = ((const float4*)spz)[tid * 4 + q];
      z[4*q+0] = c.x; z[4*q+1] = c.y; z[4*q+2] = c.z; z[4*q+3] = c.w;
    }
    const int4* i4 = (const int4*)sid + tid * 2;   // 16 u16 ids
    int4 b0 = i4[0], b1 = i4[1];
    int op[8] = { b0.x, b0.y, b0.z, b0.w, b1.x, b1.y, b1.z, b1.w };
#pragma unroll
    for (int j = 0; j < PPT; ++j) {
      int oid = (j & 1) ? ((op[j >> 1] >> 16) & 0xffff) : (op[j >> 1] & 0xffff);
      key[j] = (oid << 13) | (tid * PPT + j);
      float s = eucl2(x[j], y[j], z[j], p0x, p0y, p0z);
      if (oid == 0) { d2[j] = NEGINF; dd[j] = NEGINF; }
      else          { d2[j] = s;      dd[j] = sqrtf(s); }
    }
  }
  // ---- two Morton-tight 8-pt sub-bboxes + union ----
  float s0nx = x[0], s0ny = y[0], s0nz = z[0], s0xx = x[0], s0xy = y[0], s0xz = z[0];
#pragma unroll
  for (int j = 1; j < 8; ++j) {
    s0nx = fminf(s0nx, x[j]); s0ny = fminf(s0ny, y[j]); s0nz = fminf(s0nz, z[j]);
    s0xx = fmaxf(s0xx, x[j]); s0xy = fmaxf(s0xy, y[j]); s0xz = fmaxf(s0xz, z[j]);
  }
  float s1nx = x[8], s1ny = y[8], s1nz = z[8], s1xx = x[8], s1xy = y[8], s1xz = z[8];
#pragma unroll
  for (int j = 9; j < 16; ++j) {
    s1nx = fminf(s1nx, x[j]); s1ny = fminf(s1ny, y[j]); s1nz = fminf(s1nz, z[j]);
    s1xx = fmaxf(s1xx, x[j]); s1xy = fmaxf(s1xy, y[j]); s1xz = fmaxf(s1xz, z[j]);
  }
  const float mnx = fminf(s0nx, s1nx), mny = fminf(s0ny, s1ny), mnz = fminf(s0nz, s1nz);
  const float mxx = fmaxf(s0xx, s1xx), mxy = fmaxf(s0xy, s1xy), mxz = fmaxf(s0xz, s1xz);

  unsigned selmask = 0;
  float bv; int bkey;
  RESCAN16();
  WAVE_PUB(0);
  __syncthreads();

  for (int k = 0; k < FPS_K - 1; ++k) {
    const int p = k & 1, pn = p ^ 1;
    // ---- global winner: 8 slots, 3 DPP levels, all lanes converge ----
    const int2 sl = slots[p * 8 + (lane & 7)];
    float gv = __int_as_float(sl.x);
    int   gk = sl.y;
    dpp_sel2<0xB1>(gv, gk);    // quad_perm [1,0,3,2]
    dpp_sel2<0x4E>(gv, gk);    // quad_perm [2,3,0,1]
    dpp_sel2<0x124>(gv, gk);   // row_ror:4
    const int stor = gk & 8191;

    // ---- winner coords: one uniform broadcast read ----
    const float4 wrec = lds4[stor];
    const float wx = wrec.x, wy = wrec.y, wz = wrec.z;

    // ---- owner marks selected ----
    bool chb = false;
    if ((stor >> 4) == tid) {
      const int jj = stor & 15;
#pragma unroll
      for (int j = 0; j < PPT; ++j)
        if (j == jj) { d2[j] = NEGINF; dd[j] = NEGINF; }
      selmask |= (1u << jj);
      chb = true;
    }

    // ---- conservative gated update, d2 shadow + conditional sqrt ----
    const float lg = fmaxf(bv, 0.f);
    const float lg2 = lg * lg;
    float cx = fminf(fmaxf(wx, mnx), mxx);
    float cy = fminf(fmaxf(wy, mny), mxy);
    float cz = fminf(fmaxf(wz, mnz), mxz);
    float ddx = wx - cx, ddy = wy - cy, ddz = wz - cz;
    float bd2 = ddx * ddx + ddy * ddy + ddz * ddz;
    if (bd2 * 0.999f < lg2) {
      unsigned cm = 0;
      {
        float ax = fminf(fmaxf(wx, s0nx), s0xx);
        float ay = fminf(fmaxf(wy, s0ny), s0xy);
        float az = fminf(fmaxf(wz, s0nz), s0xz);
        float ux = wx - ax, uy = wy - ay, uz = wz - az;
        float g2 = ux * ux + uy * uy + uz * uz;
        if (g2 * 0.999f < lg2) {
#pragma unroll
          for (int j = 0; j < 8; ++j) {
            float s = eucl2(x[j], y[j], z[j], wx, wy, wz);
            if (s < d2[j]) { d2[j] = s; cm |= (1u << j); }
          }
        }
      }
      {
        float ax = fminf(fmaxf(wx, s1nx), s1xx);
        float ay = fminf(fmaxf(wy, s1ny), s1xy);
        float az = fminf(fmaxf(wz, s1nz), s1xz);
        float ux = wx - ax, uy = wy - ay, uz = wz - az;
        float g2 = ux * ux + uy * uy + uz * uz;
        if (g2 * 0.999f < lg2) {
#pragma unroll
          for (int j = 8; j < 16; ++j) {
            float s = eucl2(x[j], y[j], z[j], wx, wy, wz);
            if (s < d2[j]) { d2[j] = s; cm |= (1u << j); }
          }
        }
      }
      if (cm) {
#pragma unroll
        for (int j = 0; j < PPT; ++j)
          if ((cm >> j) & 1) dd[j] = sqrtf(d2[j]);
        if ((cm >> (bkey & 15)) & 1) chb = true;   // candidate value changed
      }
    }

    // ---- changed waves rescan + re-publish; untouched carry forward ----
    if (__ballot(chb ? 1 : 0)) {
      if (chb) { RESCAN16(); }
      WAVE_PUB(pn);
    } else {
      if (lane == wave) slots[pn * 8 + wave] = sl;   // lane==wave read row 'wave'
    }
    __syncthreads();
  }

  // ---- emit selection flags to global (orig-indexed) ----
#pragma unroll
  for (int j = 0; j < PPT; ++j)
    if ((selmask >> j) & 1) selb[key[j] >> 13] = 1;
}

// ---------------------------------------------------------------------------
// Emit selected points in ascending ORIGINAL index order (block prefix sum).
// ---------------------------------------------------------------------------
__global__ __launch_bounds__(1024) void emit_kernel(const unsigned char* __restrict__ selb,
                                                    const float* __restrict__ pos,
                                                    float* __restrict__ pos_out) {
  __shared__ int sc[1024];
  const int tid = threadIdx.x;
  int w0 = ((const int*)selb)[tid * 2 + 0];
  int w1 = ((const int*)selb)[tid * 2 + 1];
  int cnt = __popc(w0) + __popc(w1);
  sc[tid] = cnt;
  __syncthreads();
  for (int off = 1; off < 1024; off <<= 1) {
    int u = (tid >= off) ? sc[tid - off] : 0;
    __syncthreads();
    sc[tid] += u;
    __syncthreads();
  }
  int r = sc[tid] - cnt;
#pragma unroll
  for (int j = 0; j < 8; ++j) {
    int w = (j < 4) ? w0 : w1;
    if ((w >> ((j & 3) * 8)) & 1) {
      int oi = tid * 8 + j;
      pos_out[r * 3 + 0] = pos[oi * 3 + 0];
      pos_out[r * 3 + 1] = pos[oi * 3 + 1];
      pos_out[r * 3 + 2] = pos[oi * 3 + 2];
      ++r;
    }
  }
}

// ---------------------------------------------------------------------------
// W^T (256x256) into scratch (start of mask region; overwritten later).
// ---------------------------------------------------------------------------
__global__ __launch_bounds__(256) void wt_kernel(const float* __restrict__ W,
                                                 float* __restrict__ WT) {
  int i = blockIdx.x * 256 + threadIdx.x;
  int c = i >> 8, cp = i & 255;
  WT[i] = W[cp * 256 + c];
}

// ---------------------------------------------------------------------------
// Fused sparse aggregation + Linear. One block per node m.
// ---------------------------------------------------------------------------
__global__ __launch_bounds__(256) void agg_linear_kernel(
    const float* __restrict__ h, const float* __restrict__ pos,
    const float* __restrict__ nodepos, const float* __restrict__ WT,
    const float* __restrict__ bias, float* __restrict__ embed, float sb) {
  const int m = blockIdx.x;
  const int tid = threadIdx.x;
  const int lane = tid & 63, wave = tid >> 6;
  const float nx = nodepos[m * 3 + 0];
  const float ny = nodepos[m * 3 + 1];
  const float nz = nodepos[m * 3 + 2];
  const float4* h4 = (const float4*)h;

  float4 acc = make_float4(0.f, 0.f, 0.f, 0.f);
  const int base0 = wave * (FPS_N / 4);
  for (int base = base0; base < base0 + (FPS_N / 4); base += 64) {
    int n = base + lane;
    float qx = pos[n * 3 + 0], qy = pos[n * 3 + 1], qz = pos[n * 3 + 2];
    unsigned long long mb = __ballot((p3sum(qx, qy, qz, nx, ny, nz) <= sb) ? 1 : 0);
    while (mb) {
      int b = __ffsll(mb) - 1;
      mb &= (mb - 1);
      float4 hv = h4[(size_t)(base + b) * 64 + lane];
      acc.x += hv.x; acc.y += hv.y; acc.z += hv.z; acc.w += hv.w;
    }
  }

  __shared__ float lacc[4][256];
  lacc[wave][lane * 4 + 0] = acc.x;
  lacc[wave][lane * 4 + 1] = acc.y;
  lacc[wave][lane * 4 + 2] = acc.z;
  lacc[wave][lane * 4 + 3] = acc.w;
  __syncthreads();
  __shared__ float aggrow[256];
  float aggv = ((lacc[0][tid] + lacc[1][tid]) + lacc[2][tid]) + lacc[3][tid];
  aggrow[tid] = aggv;
  __syncthreads();

  float o = bias[tid];
#pragma unroll 8
  for (int c = 0; c < 256; ++c)
    o = fmaf(aggrow[c], WT[c * 256 + tid], o);
  embed[(size_t)m * 256 + tid] = o;
}

// ---------------------------------------------------------------------------
// Mask output: mask[n][m] = (sum|d|^3 <= sb) ? 1.0 : 0.0   (8192 x 4096 f32)
// ---------------------------------------------------------------------------
__global__ __launch_bounds__(256) void mask_kernel(const float* __restrict__ pos,
                                                   const float* __restrict__ nodepos,
                                                   float* __restrict__ maskout,
                                                   float sb) {
  int n  = blockIdx.y;
  int m0 = (blockIdx.x * 256 + threadIdx.x) * 4;
  float x = pos[n * 3 + 0], y = pos[n * 3 + 1], z = pos[n * 3 + 2];
  const float4* np4 = (const float4*)(nodepos + (size_t)m0 * 3);
  float4 a = np4[0], bq = np4[1], cq = np4[2];
  float4 r;
  r.x = (p3sum(x, y, z, a.x,  a.y,  a.z)  <= sb) ? 1.0f : 0.0f;
  r.y = (p3sum(x, y, z, a.w,  bq.x, bq.y) <= sb) ? 1.0f : 0.0f;
  r.z = (p3sum(x, y, z, bq.z, bq.w, cq.x) <= sb) ? 1.0f : 0.0f;
  r.w = (p3sum(x, y, z, cq.y, cq.z, cq.w) <= sb) ? 1.0f : 0.0f;
  *(float4*)(maskout + (size_t)n * FPS_K + m0) = r;
}

extern "C" void kernel_launch(void* const* d_in, const int* in_sizes, int n_in,
                              void* d_out, int out_size, void* d_ws, size_t ws_size,
                              hipStream_t stream) {
  (void)in_sizes; (void)n_in; (void)out_size; (void)d_ws; (void)ws_size;
  const float* h   = (const float*)d_in[0];
  const float* pos = (const float*)d_in[1];
  const float* W   = (const float*)d_in[2];
  const float* b   = (const float*)d_in[3];

  float* out     = (float*)d_out;
  float* embed   = out;                                   // 4096*256
  float* pos_out = out + (size_t)FPS_K * CS;              // 4096*3
  float* mask    = pos_out + (size_t)FPS_K * 3;           // 8192*4096
  float* WT      = mask;                                  // scratch (overwritten)
  float* px      = mask + (1 << 21);                      // sorted SoA scratch
  float* py      = px + FPS_N;
  float* pz      = py + FPS_N;
  unsigned short* ids16 = (unsigned short*)(pz + FPS_N);
  unsigned char*  selb  = ((unsigned char*)ids16) + 2 * FPS_N;

  // Threshold model: ref mask true  <=>  cbrt_f32(s) < 0.3f
  const float  t    = 0.3f;
  const float  ulpv = nextafterf(t, 1.0f) - t;
  const double rmid = (double)t - (double)ulpv * 0.5;
  const double C    = rmid * rmid * rmid;
  float sb = (float)C;
  if (!((double)sb < C)) sb = nextafterf(sb, 0.0f);

  hipFuncSetAttribute((const void*)fps_kernel,
                      hipFuncAttributeMaxDynamicSharedMemorySize, FPS_LDS);

  hipLaunchKernelGGL(bin_kernel, dim3(1), dim3(1024), 0, stream,
                     pos, px, py, pz, ids16, selb);
  hipLaunchKernelGGL(fps_kernel, dim3(1), dim3(FT), FPS_LDS, stream,
                     pos, px, py, pz, ids16, selb);
  hipLaunchKernelGGL(emit_kernel, dim3(1), dim3(1024), 0, stream,
                     selb, pos, pos_out);
  hipLaunchKernelGGL(wt_kernel, dim3(256), dim3(256), 0, stream, W, WT);
  hipLaunchKernelGGL(agg_linear_kernel, dim3(FPS_K), dim3(256), 0, stream,
                     h, pos, pos_out, WT, b, embed, sb);
  hipLaunchKernelGGL(mask_kernel, dim3(4, FPS_N), dim3(256), 0, stream,
                     pos, pos_out, mask, sb);
}

// Round 14
// 7813.542 us; speedup vs baseline: 1.2536x; 1.2536x over previous
//
#include <hip/hip_runtime.h>
#include <hip/hip_bf16.h>
#include <cmath>

#define FPS_N 8192
#define FPS_K 4096
#define CS    256
#define FT    1024         // FPS threads (16 waves)
#define PPT   8            // points per thread
#define NEGINF (-__builtin_inff())
#define KMAX  0x7fffffff

// Minkowski-p3 "sum of |d|^3" with reference-exact f32 op order (no FMA contraction).
__device__ __forceinline__ float p3sum(float x, float y, float z,
                                       float nx, float ny, float nz) {
  float dx = fabsf(__fsub_rn(x, nx));
  float dy = fabsf(__fsub_rn(y, ny));
  float dz = fabsf(__fsub_rn(z, nz));
  float cx = __fmul_rn(__fmul_rn(dx, dx), dx);
  float cy = __fmul_rn(__fmul_rn(dy, dy), dy);
  float cz = __fmul_rn(__fmul_rn(dz, dz), dz);
  return __fadd_rn(__fadd_rn(cx, cy), cz);
}

// Squared Euclidean distance, reference-exact f32 op order.
__device__ __forceinline__ float eucl2(float x, float y, float z,
                                       float nx, float ny, float nz) {
  float dx = __fsub_rn(x, nx);
  float dy = __fsub_rn(y, ny);
  float dz = __fsub_rn(z, nz);
  return __fadd_rn(__fadd_rn(__fmul_rn(dx, dx), __fmul_rn(dy, dy)),
                   __fmul_rn(dz, dz));
}

#define LEXGT(va, ka, vb, kb) (((va) > (vb)) || ((va) == (vb) && ((ka) < (kb))))
#define SELP(va, ka, vb, kb) { bool t_ = LEXGT(vb, kb, va, ka); \
  va = t_ ? (vb) : (va); ka = t_ ? (kb) : (ka); }

template<int CTRL>
__device__ __forceinline__ int dppi(int a) {
  return __builtin_amdgcn_update_dpp(a, a, CTRL, 0xF, 0xF, false);
}
template<int CTRL>
__device__ __forceinline__ float dppf(float a) {
  return __int_as_float(__builtin_amdgcn_update_dpp(__float_as_int(a), __float_as_int(a), CTRL, 0xF, 0xF, false));
}

// DPP lex-max select: (v,k) with v float desc, k int asc tie-break.
template<int CTRL>
__device__ __forceinline__ void dpp_sel2(float& v, int& k) {
  float fv = dppf<CTRL>(v);
  int   nk = dppi<CTRL>(k);
  bool t = LEXGT(fv, nk, v, k);
  v = t ? fv : v;
  k = t ? nk : k;
}

// lex-max select carrying (x,y,z) payload — payload DPP moves are independent
// of the compare chain (latency-free parallel). (r3/r8-proven)
template<int CTRL>
__device__ __forceinline__ void dpp_sel5(float& v, int& k, float& x, float& y, float& z) {
  float pv = dppf<CTRL>(v); int pk = dppi<CTRL>(k);
  float px = dppf<CTRL>(x); float py = dppf<CTRL>(y); float pz = dppf<CTRL>(z);
  bool t = LEXGT(pv, pk, v, k);
  v = t ? pv : v; k = t ? pk : k;
  x = t ? px : x; y = t ? py : y; z = t ? pz : z;
}

// thread-local lex-max over the 8 owned (dd, key) pairs (7 SELPs, 3 levels)
#define RESCAN() { \
  float v0 = dd[0], v1 = dd[1], v2 = dd[2], v3 = dd[3]; \
  float v4 = dd[4], v5 = dd[5], v6 = dd[6], v7 = dd[7]; \
  int j0 = key[0], j1 = key[1], j2 = key[2], j3 = key[3]; \
  int j4 = key[4], j5 = key[5], j6 = key[6], j7 = key[7]; \
  SELP(v0, j0, v1, j1) SELP(v2, j2, v3, j3) SELP(v4, j4, v5, j5) SELP(v6, j6, v7, j7) \
  SELP(v0, j0, v2, j2) SELP(v4, j4, v6, j6) SELP(v0, j0, v4, j4) \
  bv = v0; bkey = j0; }

// wave reduce (6-level DPP) + unique owner lane publishes (v,k,x,y,z) to slot
#define WAVE_PUBLISH(sn) { \
  float rv = bv; int rk = bkey; \
  dpp_sel2<0x111>(rv, rk); dpp_sel2<0x112>(rv, rk); dpp_sel2<0x114>(rv, rk); \
  dpp_sel2<0x118>(rv, rk); dpp_sel2<0x142>(rv, rk); dpp_sel2<0x143>(rv, rk); \
  int wkk = __builtin_amdgcn_readlane(rk, 63); \
  if (bkey == wkk) { \
    float sx = x[0], sy = y[0], sz = z[0]; \
    _Pragma("unroll") \
    for (int j = 0; j < PPT; ++j) \
      if (j == (bkey & 7)) { sx = x[j]; sy = y[j]; sz = z[j]; } \
    *(int4*)&sS[sn][wave][0] = make_int4(__float_as_int(bv), bkey, \
                                         __float_as_int(sx), __float_as_int(sy)); \
    sS[sn][wave][4] = __float_as_int(sz); \
  } }

// ---------------------------------------------------------------------------
// 12-bit Morton (16x16x16 over [-4,4]^3) counting sort -> SoA px/py/pz + u16
// orig ids + zeroed selection flags (orig 0 pre-marked). (r7-proven)
// ---------------------------------------------------------------------------
__global__ __launch_bounds__(1024) void bin_kernel(const float* __restrict__ pos,
                                                   float* __restrict__ px,
                                                   float* __restrict__ py,
                                                   float* __restrict__ pz,
                                                   unsigned short* __restrict__ ids16,
                                                   unsigned char* __restrict__ selb) {
  __shared__ int hist[4096];
  __shared__ int part[1024];
  const int tid = threadIdx.x;
#pragma unroll
  for (int i = 0; i < 4; ++i) hist[tid * 4 + i] = 0;
  ((int*)selb)[tid * 2 + 0] = 0;
  ((int*)selb)[tid * 2 + 1] = 0;
  if (tid == 0) selb[0] = 1;
  __syncthreads();

  float qx[8], qy[8], qz[8];
  int cell[8];
  {
    const float4* p4 = (const float4*)pos + tid * 6;
    float4 a0 = p4[0], a1 = p4[1], a2 = p4[2], a3 = p4[3], a4 = p4[4], a5 = p4[5];
    qx[0]=a0.x; qy[0]=a0.y; qz[0]=a0.z;
    qx[1]=a0.w; qy[1]=a1.x; qz[1]=a1.y;
    qx[2]=a1.z; qy[2]=a1.w; qz[2]=a2.x;
    qx[3]=a2.y; qy[3]=a2.z; qz[3]=a2.w;
    qx[4]=a3.x; qy[4]=a3.y; qz[4]=a3.z;
    qx[5]=a3.w; qy[5]=a4.x; qz[5]=a4.y;
    qx[6]=a4.z; qy[6]=a4.w; qz[6]=a5.x;
    qx[7]=a5.y; qy[7]=a5.z; qz[7]=a5.w;
  }
#pragma unroll
  for (int j = 0; j < 8; ++j) {
    int ix = min(max((int)floorf((qx[j] + 4.0f) * 2.0f), 0), 15);
    int iy = min(max((int)floorf((qy[j] + 4.0f) * 2.0f), 0), 15);
    int iz = min(max((int)floorf((qz[j] + 4.0f) * 2.0f), 0), 15);
    int m = 0;
#pragma unroll
    for (int b = 0; b < 4; ++b)
      m |= (((ix >> b) & 1) << (3 * b)) | (((iy >> b) & 1) << (3 * b + 1)) |
           (((iz >> b) & 1) << (3 * b + 2));
    cell[j] = m;
    atomicAdd(&hist[m], 1);
  }
  __syncthreads();
  int h0 = hist[tid*4], h1 = hist[tid*4+1], h2 = hist[tid*4+2], h3 = hist[tid*4+3];
  int s = h0 + h1 + h2 + h3;
  part[tid] = s;
  __syncthreads();
  for (int off = 1; off < 1024; off <<= 1) {
    int u = (tid >= off) ? part[tid - off] : 0;
    __syncthreads();
    part[tid] += u;
    __syncthreads();
  }
  int base = part[tid] - s;
  hist[tid*4+0] = base;
  hist[tid*4+1] = base + h0;
  hist[tid*4+2] = base + h0 + h1;
  hist[tid*4+3] = base + h0 + h1 + h2;
  __syncthreads();
#pragma unroll
  for (int j = 0; j < 8; ++j) {
    int slot = atomicAdd(&hist[cell[j]], 1);
    px[slot] = qx[j];
    py[slot] = qy[j];
    pz[slot] = qz[j];
    ids16[slot] = (unsigned short)(tid * 8 + j);
  }
}

// ---------------------------------------------------------------------------
// FPS: r7's structure (16 waves x 8 register points, one barrier/iter) with
// winner COORDS riding in the slots (dpp_sel5 payload merge) — removes the
// dependent coords-broadcast LDS read and the 128KB coords mirror entirely.
// Bit-exact: dd follows the reference recurrence fmin(dd, sqrt(eucl2));
// argmax tie-break = lowest ORIGINAL index via lex keys at every level;
// bbox gates conservative (0.999 margin).
// ---------------------------------------------------------------------------
__global__ __launch_bounds__(FT) void fps_kernel(const float* __restrict__ pos,
                                                 const float* __restrict__ spx,
                                                 const float* __restrict__ spy,
                                                 const float* __restrict__ spz,
                                                 const unsigned short* __restrict__ sid,
                                                 unsigned char* __restrict__ selb) {
  __shared__ __align__(16) int sS[2][16][8];   // [parity][wave][v,k,x,y,z,pad3]
  const int tid = threadIdx.x, lane = tid & 63, wave = tid >> 6;

  float x[PPT], y[PPT], z[PPT], dd[PPT];
  int key[PPT];
  const float p0x = pos[0], p0y = pos[1], p0z = pos[2];
  {
    int4 b0 = ((const int4*)sid)[tid];   // 8 u16 orig ids
    int op[4] = { b0.x, b0.y, b0.z, b0.w };
#pragma unroll
    for (int j = 0; j < PPT; ++j) {
      int oid = (j & 1) ? ((op[j >> 1] >> 16) & 0xffff) : (op[j >> 1] & 0xffff);
      key[j] = (oid << 13) | (tid * PPT + j);
      float X = spx[tid * PPT + j], Y = spy[tid * PPT + j], Z = spz[tid * PPT + j];
      x[j] = X; y[j] = Y; z[j] = Z;
      float s = eucl2(X, Y, Z, p0x, p0y, p0z);
      dd[j] = (oid == 0) ? NEGINF : sqrtf(s);
    }
  }
  // thread bbox (tight: 8-pt Morton run)
  float mnx = x[0], mny = y[0], mnz = z[0], mxx = x[0], mxy = y[0], mxz = z[0];
#pragma unroll
  for (int j = 1; j < PPT; ++j) {
    mnx = fminf(mnx, x[j]); mny = fminf(mny, y[j]); mnz = fminf(mnz, z[j]);
    mxx = fmaxf(mxx, x[j]); mxy = fmaxf(mxy, y[j]); mxz = fmaxf(mxz, z[j]);
  }

  unsigned selmask = 0;
  float bv; int bkey;
  RESCAN();
  WAVE_PUBLISH(0);
  __syncthreads();

  for (int k = 0; k < FPS_K - 1; ++k) {
    const int p = k & 1, pn = p ^ 1;
    // ---- read 16 slot rows (coords included; two parallel LDS reads) ----
    const int row = lane & 15;
    const int4 q0 = *(const int4*)&sS[p][row][0];
    const int  qz4 = sS[p][row][4];
    float gv = __int_as_float(q0.x);
    int   gk = q0.y;
    float gx = __int_as_float(q0.z);
    float gy = __int_as_float(q0.w);
    float gz = __int_as_float(qz4);

    // ---- 4-level sel5 merge: winner (v,k,x,y,z) in all lanes ----
    dpp_sel5<0xB1>(gv, gk, gx, gy, gz);    // quad_perm [1,0,3,2]
    dpp_sel5<0x4E>(gv, gk, gx, gy, gz);    // quad_perm [2,3,0,1]
    dpp_sel5<0x124>(gv, gk, gx, gy, gz);   // row_ror:4
    dpp_sel5<0x128>(gv, gk, gx, gy, gz);   // row_ror:8
    const int stor = gk & 8191;
    const float wx = gx, wy = gy, wz = gz;

    // ---- owner marks selected ----
    bool own = false;
    if ((stor >> 3) == tid) {
      const int jj = stor & 7;
#pragma unroll
      for (int j = 0; j < PPT; ++j) if (j == jj) dd[j] = NEGINF;
      selmask |= (1u << jj);
      own = true;
    }

    // ---- conservative bbox gate + reference-exact update ----
    const float lg = fmaxf(bv, 0.f);
    float cx = fminf(fmaxf(wx, mnx), mxx);
    float cy = fminf(fmaxf(wy, mny), mxy);
    float cz = fminf(fmaxf(wz, mnz), mxz);
    float ddx = wx - cx, ddy = wy - cy, ddz = wz - cz;
    float bd2 = ddx * ddx + ddy * ddy + ddz * ddz;
    const bool fire = (bd2 * 0.999f < lg * lg);
    if (fire) {
#pragma unroll
      for (int j = 0; j < PPT; ++j)
        dd[j] = fminf(dd[j], sqrtf(eucl2(x[j], y[j], z[j], wx, wy, wz)));
    }

    // ---- hit waves refresh + publish; untouched waves carry forward ----
    if (__ballot((fire || own) ? 1 : 0)) {
      if (fire || own) { RESCAN(); }
      WAVE_PUBLISH(pn);
    } else {
      if (lane == wave) {   // lane==wave read row 'wave' (wave < 16)
        *(int4*)&sS[pn][wave][0] = q0;
        sS[pn][wave][4] = qz4;
      }
    }
    __syncthreads();
  }

  // ---- emit selection flags to global (orig-indexed) ----
#pragma unroll
  for (int j = 0; j < PPT; ++j)
    if ((selmask >> j) & 1) selb[key[j] >> 13] = 1;
}

// ---------------------------------------------------------------------------
// Emit selected points in ascending ORIGINAL index order (block prefix sum).
// ---------------------------------------------------------------------------
__global__ __launch_bounds__(1024) void emit_kernel(const unsigned char* __restrict__ selb,
                                                    const float* __restrict__ pos,
                                                    float* __restrict__ pos_out) {
  __shared__ int sc[1024];
  const int tid = threadIdx.x;
  int w0 = ((const int*)selb)[tid * 2 + 0];
  int w1 = ((const int*)selb)[tid * 2 + 1];
  int cnt = __popc(w0) + __popc(w1);
  sc[tid] = cnt;
  __syncthreads();
  for (int off = 1; off < 1024; off <<= 1) {
    int u = (tid >= off) ? sc[tid - off] : 0;
    __syncthreads();
    sc[tid] += u;
    __syncthreads();
  }
  int r = sc[tid] - cnt;
#pragma unroll
  for (int j = 0; j < 8; ++j) {
    int w = (j < 4) ? w0 : w1;
    if ((w >> ((j & 3) * 8)) & 1) {
      int oi = tid * 8 + j;
      pos_out[r * 3 + 0] = pos[oi * 3 + 0];
      pos_out[r * 3 + 1] = pos[oi * 3 + 1];
      pos_out[r * 3 + 2] = pos[oi * 3 + 2];
      ++r;
    }
  }
}

// ---------------------------------------------------------------------------
// W^T (256x256) into scratch (start of mask region; overwritten later).
// ---------------------------------------------------------------------------
__global__ __launch_bounds__(256) void wt_kernel(const float* __restrict__ W,
                                                 float* __restrict__ WT) {
  int i = blockIdx.x * 256 + threadIdx.x;
  int c = i >> 8, cp = i & 255;
  WT[i] = W[cp * 256 + c];
}

// ---------------------------------------------------------------------------
// Fused sparse aggregation + Linear. One block per node m.
// ---------------------------------------------------------------------------
__global__ __launch_bounds__(256) void agg_linear_kernel(
    const float* __restrict__ h, const float* __restrict__ pos,
    const float* __restrict__ nodepos, const float* __restrict__ WT,
    const float* __restrict__ bias, float* __restrict__ embed, float sb) {
  const int m = blockIdx.x;
  const int tid = threadIdx.x;
  const int lane = tid & 63, wave = tid >> 6;
  const float nx = nodepos[m * 3 + 0];
  const float ny = nodepos[m * 3 + 1];
  const float nz = nodepos[m * 3 + 2];
  const float4* h4 = (const float4*)h;

  float4 acc = make_float4(0.f, 0.f, 0.f, 0.f);
  const int base0 = wave * (FPS_N / 4);
  for (int base = base0; base < base0 + (FPS_N / 4); base += 64) {
    int n = base + lane;
    float qx = pos[n * 3 + 0], qy = pos[n * 3 + 1], qz = pos[n * 3 + 2];
    unsigned long long mb = __ballot((p3sum(qx, qy, qz, nx, ny, nz) <= sb) ? 1 : 0);
    while (mb) {
      int b = __ffsll(mb) - 1;
      mb &= (mb - 1);
      float4 hv = h4[(size_t)(base + b) * 64 + lane];
      acc.x += hv.x; acc.y += hv.y; acc.z += hv.z; acc.w += hv.w;
    }
  }

  __shared__ float lacc[4][256];
  lacc[wave][lane * 4 + 0] = acc.x;
  lacc[wave][lane * 4 + 1] = acc.y;
  lacc[wave][lane * 4 + 2] = acc.z;
  lacc[wave][lane * 4 + 3] = acc.w;
  __syncthreads();
  __shared__ float aggrow[256];
  float aggv = ((lacc[0][tid] + lacc[1][tid]) + lacc[2][tid]) + lacc[3][tid];
  aggrow[tid] = aggv;
  __syncthreads();

  float o = bias[tid];
#pragma unroll 8
  for (int c = 0; c < 256; ++c)
    o = fmaf(aggrow[c], WT[c * 256 + tid], o);
  embed[(size_t)m * 256 + tid] = o;
}

// ---------------------------------------------------------------------------
// Mask output: mask[n][m] = (sum|d|^3 <= sb) ? 1.0 : 0.0   (8192 x 4096 f32)
// ---------------------------------------------------------------------------
__global__ __launch_bounds__(256) void mask_kernel(const float* __restrict__ pos,
                                                   const float* __restrict__ nodepos,
                                                   float* __restrict__ maskout,
                                                   float sb) {
  int n  = blockIdx.y;
  int m0 = (blockIdx.x * 256 + threadIdx.x) * 4;
  float x = pos[n * 3 + 0], y = pos[n * 3 + 1], z = pos[n * 3 + 2];
  const float4* np4 = (const float4*)(nodepos + (size_t)m0 * 3);
  float4 a = np4[0], bq = np4[1], cq = np4[2];
  float4 r;
  r.x = (p3sum(x, y, z, a.x,  a.y,  a.z)  <= sb) ? 1.0f : 0.0f;
  r.y = (p3sum(x, y, z, a.w,  bq.x, bq.y) <= sb) ? 1.0f : 0.0f;
  r.z = (p3sum(x, y, z, bq.z, bq.w, cq.x) <= sb) ? 1.0f : 0.0f;
  r.w = (p3sum(x, y, z, cq.y, cq.z, cq.w) <= sb) ? 1.0f : 0.0f;
  *(float4*)(maskout + (size_t)n * FPS_K + m0) = r;
}

extern "C" void kernel_launch(void* const* d_in, const int* in_sizes, int n_in,
                              void* d_out, int out_size, void* d_ws, size_t ws_size,
                              hipStream_t stream) {
  (void)in_sizes; (void)n_in; (void)out_size; (void)d_ws; (void)ws_size;
  const float* h   = (const float*)d_in[0];
  const float* pos = (const float*)d_in[1];
  const float* W   = (const float*)d_in[2];
  const float* b   = (const float*)d_in[3];

  float* out     = (float*)d_out;
  float* embed   = out;                                   // 4096*256
  float* pos_out = out + (size_t)FPS_K * CS;              // 4096*3
  float* mask    = pos_out + (size_t)FPS_K * 3;           // 8192*4096
  float* WT      = mask;                                  // scratch (overwritten)
  float* px      = mask + (1 << 21);                      // sorted SoA scratch
  float* py      = px + FPS_N;
  float* pz      = py + FPS_N;
  unsigned short* ids16 = (unsigned short*)(pz + FPS_N);
  unsigned char*  selb  = ((unsigned char*)ids16) + 2 * FPS_N;

  // Threshold model: ref mask true  <=>  cbrt_f32(s) < 0.3f
  const float  t    = 0.3f;
  const float  ulpv = nextafterf(t, 1.0f) - t;
  const double rmid = (double)t - (double)ulpv * 0.5;
  const double C    = rmid * rmid * rmid;
  float sb = (float)C;
  if (!((double)sb < C)) sb = nextafterf(sb, 0.0f);

  hipLaunchKernelGGL(bin_kernel, dim3(1), dim3(1024), 0, stream,
                     pos, px, py, pz, ids16, selb);
  hipLaunchKernelGGL(fps_kernel, dim3(1), dim3(FT), 0, stream,
                     pos, px, py, pz, ids16, selb);
  hipLaunchKernelGGL(emit_kernel, dim3(1), dim3(1024), 0, stream,
                     selb, pos, pos_out);
  hipLaunchKernelGGL(wt_kernel, dim3(256), dim3(256), 0, stream, W, WT);
  hipLaunchKernelGGL(agg_linear_kernel, dim3(FPS_K), dim3(256), 0, stream,
                     h, pos, pos_out, WT, b, embed, sb);
  hipLaunchKernelGGL(mask_kernel, dim3(4, FPS_N), dim3(256), 0, stream,
                     pos, pos_out, mask, sb);
}